// Round 1
// baseline (10.806 us; speedup 1.0000x reference)
//
#include <hip/hip_runtime.h>

// CenterLoss: B=1024, D=128, C=100000.
// Exact algebraic collapse of the reference:
//   out = (1/B) * sum_b clip(||x_b - centers[labels_b]||^2, 1e-12, 1e12)
//         + (C-1) * 1e-12                  // the B*(C-1) masked zeros clamped up
// Only the B label-indexed center rows are ever needed.

#define CL_B 1024
#define CL_D 128
#define CL_C 100000

// One wave (64 lanes) per sample. Lane t handles elements [2t, 2t+1] via float2.
__global__ __launch_bounds__(64) void cl_per_sample(
    const float* __restrict__ x,
    const int* __restrict__ labels,
    const float* __restrict__ centers,
    float* __restrict__ ws) {
    const int b = blockIdx.x;
    const int t = threadIdx.x;                 // 0..63
    const int lab = labels[b];

    const float2* xp = reinterpret_cast<const float2*>(x + (size_t)b * CL_D);
    const float2* cp = reinterpret_cast<const float2*>(centers + (size_t)lab * CL_D);
    const float2 xv = xp[t];
    const float2 cv = cp[t];
    const float d0 = xv.x - cv.x;
    const float d1 = xv.y - cv.y;
    float s = d0 * d0 + d1 * d1;

    // 64-lane butterfly reduce (wave = 64 on CDNA).
    #pragma unroll
    for (int off = 32; off > 0; off >>= 1)
        s += __shfl_down(s, off, 64);

    if (t == 0) {
        s = fminf(fmaxf(s, 1e-12f), 1e12f);    // clip, matching reference
        ws[b] = s;
    }
}

// Single block reduces the 1024 per-sample distances.
__global__ __launch_bounds__(256) void cl_reduce(
    const float* __restrict__ ws,
    float* __restrict__ out) {
    const int t = threadIdx.x;                 // 0..255
    float s = 0.0f;
    #pragma unroll
    for (int i = 0; i < CL_B / 256; ++i)
        s += ws[t + i * 256];

    #pragma unroll
    for (int off = 32; off > 0; off >>= 1)
        s += __shfl_down(s, off, 64);

    __shared__ float sm[4];
    if ((t & 63) == 0) sm[t >> 6] = s;
    __syncthreads();
    if (t == 0) {
        const float tot = sm[0] + sm[1] + sm[2] + sm[3];
        // mean over B, plus the clamped off-label zeros: B*(C-1)*1e-12 / B.
        out[0] = tot / (float)CL_B + (float)(CL_C - 1) * 1e-12f;
    }
}

extern "C" void kernel_launch(void* const* d_in, const int* in_sizes, int n_in,
                              void* d_out, int out_size, void* d_ws, size_t ws_size,
                              hipStream_t stream) {
    const float* x       = (const float*)d_in[0];   // [1024, 128] f32
    const int*   labels  = (const int*)d_in[1];     // [1024] int
    const float* centers = (const float*)d_in[2];   // [100000, 128] f32
    float* out = (float*)d_out;                      // [1] f32
    float* ws  = (float*)d_ws;                       // >= 4 KB scratch

    cl_per_sample<<<CL_B, 64, 0, stream>>>(x, labels, centers, ws);
    cl_reduce<<<1, 256, 0, stream>>>(ws, out);
}